// Round 1
// 267.045 us; speedup vs baseline: 1.0056x; 1.0056x over previous
//
#include <hip/hip_runtime.h>

#define N_NODES 100000
#define C_DIM 128
#define E_EDGES 800000
#define V_OUT 50000
#define EN (E_EDGES + N_NODES)      /* 900000  per-layer CSR entries */
#define M2 (2 * N_NODES)
#define EN2 (2 * EN)                /* 1800000 */

#define BSHIFT 9                    /* 512 nodes per coarse bucket */
#define NBUCK_L ((N_NODES + 511) >> 9)   /* 196 per layer */
#define NBUCK2 (2 * NBUCK_L)             /* 392 */
#define CAP 8192                    /* slab capacity; avg fill ~4608 */
#define P1_CHUNK 4096
#define P1_PER_T (P1_CHUNK / 256)   /* 16 */
#define NCHUNK ((EN2 + P1_CHUNK - 1) / P1_CHUNK) /* 440 */

#define XPAD 136                    /* LDS row stride (ushorts): 272B, 2-way banks */
#define LDS_E 768                   /* staged edges per 32-node block; mean 288, 30 sigma safe */

typedef unsigned int uint;
typedef unsigned short ushort;
typedef __attribute__((ext_vector_type(8))) short bf16x8;
typedef __attribute__((ext_vector_type(4))) float f32x4;

static __device__ __forceinline__ ushort f2bf(float f) {
    uint u = __float_as_uint(f);
    u += 0x7fffu + ((u >> 16) & 1);   // round-to-nearest-even
    return (ushort)(u >> 16);
}

// ---------------------------------------------------------------------------
// prep: convert W1,W2 to bf16 + scatter vflag, one fused kernel.
// ---------------------------------------------------------------------------
#define PREP_WBLK (C_DIM * C_DIM / 4 / 256)   /* 16 */
#define PREP_VBLK ((V_OUT + 255) / 256)       /* 196 */
__global__ void prep_kernel(const float* __restrict__ W1, const float* __restrict__ W2,
                            ushort* __restrict__ W1b, ushort* __restrict__ W2b,
                            const int* __restrict__ idx, int* __restrict__ vflag)
{
    const int b = blockIdx.x;
    if (b < 2 * PREP_WBLK) {
        const float* in  = (b < PREP_WBLK) ? W1 : W2;
        ushort* outp     = (b < PREP_WBLK) ? W1b : W2b;
        int i = (b % PREP_WBLK) * 256 + threadIdx.x;
        float4 v = reinterpret_cast<const float4*>(in)[i];
        ushort4 r;
        r.x = f2bf(v.x); r.y = f2bf(v.y); r.z = f2bf(v.z); r.w = f2bf(v.w);
        reinterpret_cast<ushort4*>(outp)[i] = r;
    } else {
        int v = (b - 2 * PREP_WBLK) * 256 + threadIdx.x;
        if (v < V_OUT) vflag[idx[v]] = 1;    // races benign: all write 1
    }
}

// ---------------------------------------------------------------------------
// MFMA GEMM, LDS-staged: block = 64 nodes (4 waves x 16-node tiles).
// ---------------------------------------------------------------------------
template <int IN_F32>
__global__ __launch_bounds__(256) void gemm_mfma(
    const void* __restrict__ xin, const ushort* __restrict__ Wb,
    const float* __restrict__ att_s, const float* __restrict__ att_d,
    ushort* __restrict__ hb, float* __restrict__ a_s, float* __restrict__ a_d)
{
    __shared__ ushort xs[64 * XPAD];    // 17.4 KB
    __shared__ ushort ws[128 * XPAD];   // 34.8 KB
    const int tid = threadIdx.x;
    const int nb = blockIdx.x * 64;

    // ---- stage X: thread t -> row t>>2 (clamped), quarter t&3 ------------
    {
        const int row = tid >> 2, q = tid & 3;
        const long srow = min(nb + row, N_NODES - 1);
        ushort* dst = &xs[row * XPAD + q * 32];
        if (IN_F32) {
            const float* src = (const float*)xin + srow * 128 + q * 32;
            #pragma unroll
            for (int i = 0; i < 4; ++i) {
                float4 u = *reinterpret_cast<const float4*>(src + i * 8);
                float4 v = *reinterpret_cast<const float4*>(src + i * 8 + 4);
                uint4 pk;
                pk.x = (uint)f2bf(u.x) | ((uint)f2bf(u.y) << 16);
                pk.y = (uint)f2bf(u.z) | ((uint)f2bf(u.w) << 16);
                pk.z = (uint)f2bf(v.x) | ((uint)f2bf(v.y) << 16);
                pk.w = (uint)f2bf(v.z) | ((uint)f2bf(v.w) << 16);
                *reinterpret_cast<uint4*>(dst + i * 8) = pk;
            }
        } else {
            const ushort* src = (const ushort*)xin + srow * 128 + q * 32;
            #pragma unroll
            for (int i = 0; i < 4; ++i)
                *reinterpret_cast<uint4*>(dst + i * 8) =
                    *reinterpret_cast<const uint4*>(src + i * 8);
        }
    }
    // ---- stage W: thread t -> row t>>1, half t&1 --------------------------
    {
        const int row = tid >> 1, half = tid & 1;
        const ushort* src = Wb + row * 128 + half * 64;
        ushort* dst = &ws[row * XPAD + half * 64];
        #pragma unroll
        for (int i = 0; i < 8; ++i)
            *reinterpret_cast<uint4*>(dst + i * 8) =
                *reinterpret_cast<const uint4*>(src + i * 8);
    }
    __syncthreads();

    const int lane = tid & 63;
    const int wv   = tid >> 6;
    const int n0   = nb + wv * 16;        // N % 16 == 0: tiles never partial
    if (n0 >= N_NODES) return;
    const int m    = lane & 15;
    const int quad = lane >> 4;

    bf16x8 a[4];
    #pragma unroll
    for (int ki = 0; ki < 4; ++ki)
        a[ki] = *reinterpret_cast<const bf16x8*>(&xs[(wv * 16 + m) * XPAD + quad * 8 + ki * 32]);

    float ps[4] = {0, 0, 0, 0}, pd[4] = {0, 0, 0, 0};

    #pragma unroll
    for (int ct = 0; ct < 8; ++ct) {
        const int c = ct * 16 + m;
        f32x4 acc = {0.f, 0.f, 0.f, 0.f};
        #pragma unroll
        for (int ki = 0; ki < 4; ++ki) {
            bf16x8 b = *reinterpret_cast<const bf16x8*>(&ws[c * XPAD + quad * 8 + ki * 32]);
            acc = __builtin_amdgcn_mfma_f32_16x16x32_bf16(a[ki], b, acc, 0, 0, 0);
        }
        const float asc = att_s[c], adc = att_d[c];
        #pragma unroll
        for (int r = 0; r < 4; ++r) {
            const int node = n0 + quad * 4 + r;
            hb[(long)node * 128 + c] = f2bf(acc[r]);
            ps[r] = fmaf(acc[r], asc, ps[r]);
            pd[r] = fmaf(acc[r], adc, pd[r]);
        }
    }
    #pragma unroll
    for (int r = 0; r < 4; ++r) {
        float s = ps[r], d = pd[r];
        #pragma unroll
        for (int x = 1; x < 16; x <<= 1) { s += __shfl_xor(s, x); d += __shfl_xor(d, x); }
        if (m == 0) {
            const int node = n0 + quad * 4 + r;
            a_s[node] = s; a_d[node] = d;
        }
    }
}

// ---------------------------------------------------------------------------
// CSR build, pass 1: partition edges into 392 coarse buckets of 512 dst.
// ---------------------------------------------------------------------------
__global__ __launch_bounds__(256) void partition_kernel(
    const int* __restrict__ e1, const int* __restrict__ e2,
    int* __restrict__ cursor, uint* __restrict__ slab)
{
    __shared__ int cnt[NBUCK2];
    __shared__ int basearr[NBUCK2];
    const int tid = threadIdx.x;
    for (int i = tid; i < NBUCK2; i += 256) cnt[i] = 0;
    __syncthreads();

    const int e0 = blockIdx.x * P1_CHUNK;
    uint ent[P1_PER_T];
    int  bkt[P1_PER_T];
    #pragma unroll
    for (int i = 0; i < P1_PER_T; ++i) {
        int e = e0 + i * 256 + tid;
        bkt[i] = -1;
        if (e < EN2) {
            int src, dst, lb;
            if (e < EN) {
                if (e < E_EDGES) { src = e1[e]; dst = e1[E_EDGES + e]; }
                else             { src = dst = e - E_EDGES; }
                lb = 0;
            } else {
                int f = e - EN;
                if (f < E_EDGES) { src = e2[f]; dst = e2[E_EDGES + f]; }
                else             { src = dst = f - E_EDGES; }
                lb = NBUCK_L;
            }
            bkt[i] = lb + (dst >> BSHIFT);
            ent[i] = (uint)src | ((uint)(dst & 511) << 17);
            atomicAdd(&cnt[bkt[i]], 1);
        }
    }
    __syncthreads();
    for (int b = tid; b < NBUCK2; b += 256) {
        int c = cnt[b];
        basearr[b] = (c > 0) ? atomicAdd(&cursor[b], c) : 0;
        cnt[b] = 0;                       // reuse as rank counter
    }
    __syncthreads();
    #pragma unroll
    for (int i = 0; i < P1_PER_T; ++i) {
        if (bkt[i] >= 0) {
            int r = basearr[bkt[i]] + atomicAdd(&cnt[bkt[i]], 1);
            if (r < CAP) slab[(long)bkt[i] * CAP + r] = ent[i];
        }
    }
}

// exclusive scan of the 392 bucket counts; single wave
__global__ void bucket_scan(const int* __restrict__ cursor, int* __restrict__ bbase)
{
    const int lane = threadIdx.x;     // 64 threads
    int v[7]; int s = 0;
    #pragma unroll
    for (int i = 0; i < 7; ++i) {
        int idx = lane * 7 + i;
        v[i] = (idx < NBUCK2) ? cursor[idx] : 0;
        s += v[i];
    }
    int incl = s;
    #pragma unroll
    for (int d = 1; d < 64; d <<= 1) {
        int t = __shfl_up(incl, d);
        if (lane >= d) incl += t;
    }
    int excl = incl - s;
    #pragma unroll
    for (int i = 0; i < 7; ++i) {
        int idx = lane * 7 + i;
        if (idx < NBUCK2) bbase[idx] = excl;
        excl += v[i];
    }
}

// ---------------------------------------------------------------------------
// CSR build, pass 2: one workgroup per bucket -> local CSR in LDS.
// esrc entries stay PACKED (src | dst_local<<17).
// ---------------------------------------------------------------------------
__global__ __launch_bounds__(256) void local_csr(
    const uint* __restrict__ slab, const int* __restrict__ cursor,
    const int* __restrict__ bbase, int* __restrict__ offs, uint* __restrict__ esrc)
{
    __shared__ uint ent[CAP];         // 32 KB
    __shared__ int deg[512];
    __shared__ int excl[512];
    const int b = blockIdx.x;
    const int tid = threadIdx.x;
    const int cnt = min(cursor[b], CAP);
    const int base = bbase[b];
    const int layer = (b >= NBUCK_L);
    const int node0 = (b - layer * NBUCK_L) << BSHIFT;
    const int obase = layer * N_NODES;
    const int nodes_n = min(512, N_NODES - node0);

    for (int i = tid; i < 512; i += 256) deg[i] = 0;
    __syncthreads();
    for (int i = tid; i < cnt; i += 256) {
        uint v = slab[(long)b * CAP + i];
        ent[i] = v;
        atomicAdd(&deg[v >> 17], 1);
    }
    __syncthreads();
    if (tid < 64) {                   // wave-0 scan of deg[512], 8 per lane
        int v8[8]; int s = 0;
        #pragma unroll
        for (int i = 0; i < 8; ++i) { v8[i] = deg[tid * 8 + i]; s += v8[i]; }
        int incl = s;
        #pragma unroll
        for (int d = 1; d < 64; d <<= 1) {
            int t = __shfl_up(incl, d);
            if (tid >= d) incl += t;
        }
        int e = incl - s;
        #pragma unroll
        for (int i = 0; i < 8; ++i) { excl[tid * 8 + i] = e; e += v8[i]; }
    }
    __syncthreads();
    for (int i = tid; i < nodes_n; i += 256)
        offs[obase + node0 + i] = base + excl[i];
    for (int i = tid; i < 512; i += 256) deg[i] = 0;   // reuse as rank ctr
    if (tid == 0 && node0 + 512 >= N_NODES)
        offs[obase + N_NODES] = base + cnt;            // layer sentinel
    __syncthreads();
    for (int i = tid; i < cnt; i += 256) {
        uint v = ent[i];
        int dl = v >> 17;
        int r = atomicAdd(&deg[dl], 1);
        esrc[base + excl[dl] + r] = v;                 // packed src|dl<<17
    }
}

// ---------------------------------------------------------------------------
// Softmax aggregation, TWO-PHASE, 2 chains/slot: block = 32 nodes whose esrc
// range is one contiguous span (32 | 512, blocks never straddle buckets).
// Phase 1 (edge-parallel): compute w = exp(leaky(a_s[src]+a_d[dst])) for the
//   block's ~290 edges; stash {packed_v, w} as uint2 in LDS. ALWAYS writes a
//   valid packed v (MODE 1 gates only the gather+exp, storing w=0) so the
//   clamped pipeline below never reads garbage addresses.
// Phase 2 (slot loop): 4 slots/wave, each slot owns TWO adjacent nodes with
//   two independent software-pipelined edge chains -> ~4 global row-loads in
//   flight per wave (2x the 1-chain version). Chains are clamped-index +
//   w-masked so the combined loop is branch-free; the shorter chain re-reads
//   its last row (L2-hit, latency-hidden).
// Overflow (block edges > LDS_E, prob ~0): slow correct path from global.
// MODE 1 skips nodes with vflag==0 (self-loop guarantees len>0 for flagged).
// ---------------------------------------------------------------------------
template <int MODE>
__global__ __launch_bounds__(256) void aggregate(
    const ushort* __restrict__ hb, const float* __restrict__ a_s,
    const float* __restrict__ a_d, const float* __restrict__ bias,
    const int* __restrict__ offs, const uint* __restrict__ esrc,
    const int* __restrict__ vflag, void* __restrict__ outp, int obase)
{
    __shared__ uint2 ew[LDS_E];       // 6 KB
    const int tid = threadIdx.x;
    const int node0 = blockIdx.x * 32;            // grid = N/32 = 3125
    const int bnode0 = (node0 >> BSHIFT) << BSHIFT;  // bucket's first node (layer-local)
    const int bstart = offs[obase + node0];
    const int bend   = offs[obase + node0 + 32];
    const int nE = bend - bstart;

    // ---- phase 1: stage {v, w} for the block's edges ---------------------
    for (int i = tid; i < min(nE, LDS_E); i += 256) {
        uint v = esrc[bstart + i];
        float w = 0.0f;
        const int d = bnode0 + (v >> 17);
        if (MODE == 0 || vflag[d] != 0) {
            float e = a_s[v & 0x1ffff] + a_d[d];
            e = (e >= 0.0f) ? e : 0.2f * e;
            w = __expf(e);
        }
        ew[i] = make_uint2(v, __float_as_uint(w));
    }
    __syncthreads();

    // ---- phase 2: slot loop, 2 nodes per slot ----------------------------
    const int wave = tid >> 6;
    const int lane = tid & 63;
    const int slot = lane >> 4;
    const int c16  = lane & 15;
    const int nA = node0 + wave * 8 + slot * 2;
    const int nB = nA + 1;

    const int sA   = offs[obase + nA];
    const int sB   = offs[obase + nA + 1];        // end(A) == start(B)
    const int eBnd = offs[obase + nB + 1];

    int lenA = sB - sA;
    int lenB = eBnd - sB;
    int flagA = 1, flagB = 1;
    if (MODE == 1) {
        flagA = vflag[nA]; flagB = vflag[nB];
        if (!flagA) lenA = 0;
        if (!flagB) lenB = 0;
    }
    const int L = max(lenA, lenB);
    if (L == 0) return;                           // both nodes skipped

    const long coff = (long)(c16 << 3);
    float accA[8] = {0, 0, 0, 0, 0, 0, 0, 0};
    float accB[8] = {0, 0, 0, 0, 0, 0, 0, 0};
    float dsumA = 0.0f, dsumB = 0.0f;

    if (nE <= LDS_E) {
        // fast path: per-edge state from LDS, two interleaved pipelines
        const int jA = sA - bstart, jB = sB - bstart;
        const int hiA = (lenA > 0) ? (jA + lenA - 1) : 0;   // ew[0] always valid (nE>0)
        const int hiB = (lenB > 0) ? (jB + lenB - 1) : 0;
        uint2 pa0 = ew[min(jA,     hiA)];
        uint2 pa1 = ew[min(jA + 1, hiA)];
        uint2 pa2 = ew[min(jA + 2, hiA)];
        uint2 pb0 = ew[min(jB,     hiB)];
        uint2 pb1 = ew[min(jB + 1, hiB)];
        uint2 pb2 = ew[min(jB + 2, hiB)];
        uint4 hA0 = *reinterpret_cast<const uint4*>(hb + ((long)(pa0.x & 0x1ffff) << 7) + coff);
        uint4 hB0 = *reinterpret_cast<const uint4*>(hb + ((long)(pb0.x & 0x1ffff) << 7) + coff);
        uint4 hA1 = *reinterpret_cast<const uint4*>(hb + ((long)(pa1.x & 0x1ffff) << 7) + coff);
        uint4 hB1 = *reinterpret_cast<const uint4*>(hb + ((long)(pb1.x & 0x1ffff) << 7) + coff);
        float wA0 = __uint_as_float(pa0.y), wA1 = __uint_as_float(pa1.y);
        float wB0 = __uint_as_float(pb0.y), wB1 = __uint_as_float(pb1.y);
        for (int t = 0; t < L; ++t) {
            uint2 pa3 = ew[min(jA + t + 3, hiA)];
            uint2 pb3 = ew[min(jB + t + 3, hiB)];
            uint4 hA2 = *reinterpret_cast<const uint4*>(hb + ((long)(pa2.x & 0x1ffff) << 7) + coff);
            uint4 hB2 = *reinterpret_cast<const uint4*>(hb + ((long)(pb2.x & 0x1ffff) << 7) + coff);
            float wA2 = __uint_as_float(pa2.y);
            float wB2 = __uint_as_float(pb2.y);
            const float wa = (t < lenA) ? wA0 : 0.0f;
            const float wb = (t < lenB) ? wB0 : 0.0f;
            dsumA += wa; dsumB += wb;
            accA[0] = fmaf(wa, __uint_as_float(hA0.x << 16),         accA[0]);
            accA[1] = fmaf(wa, __uint_as_float(hA0.x & 0xffff0000u), accA[1]);
            accA[2] = fmaf(wa, __uint_as_float(hA0.y << 16),         accA[2]);
            accA[3] = fmaf(wa, __uint_as_float(hA0.y & 0xffff0000u), accA[3]);
            accA[4] = fmaf(wa, __uint_as_float(hA0.z << 16),         accA[4]);
            accA[5] = fmaf(wa, __uint_as_float(hA0.z & 0xffff0000u), accA[5]);
            accA[6] = fmaf(wa, __uint_as_float(hA0.w << 16),         accA[6]);
            accA[7] = fmaf(wa, __uint_as_float(hA0.w & 0xffff0000u), accA[7]);
            accB[0] = fmaf(wb, __uint_as_float(hB0.x << 16),         accB[0]);
            accB[1] = fmaf(wb, __uint_as_float(hB0.x & 0xffff0000u), accB[1]);
            accB[2] = fmaf(wb, __uint_as_float(hB0.y << 16),         accB[2]);
            accB[3] = fmaf(wb, __uint_as_float(hB0.y & 0xffff0000u), accB[3]);
            accB[4] = fmaf(wb, __uint_as_float(hB0.z << 16),         accB[4]);
            accB[5] = fmaf(wb, __uint_as_float(hB0.z & 0xffff0000u), accB[5]);
            accB[6] = fmaf(wb, __uint_as_float(hB0.w << 16),         accB[6]);
            accB[7] = fmaf(wb, __uint_as_float(hB0.w & 0xffff0000u), accB[7]);
            wA0 = wA1; wA1 = wA2; hA0 = hA1; hA1 = hA2; pa2 = pa3;
            wB0 = wB1; wB1 = wB2; hB0 = hB1; hB1 = hB2; pb2 = pb3;
        }
    } else {
        // slow correct path (never taken in practice)
        if (lenA > 0) {
            const float ad = a_d[nA];
            for (int j = sA; j < sB; ++j) {
                uint v = esrc[j];
                float e = a_s[v & 0x1ffff] + ad;
                e = (e >= 0.0f) ? e : 0.2f * e;
                float w = __expf(e);
                uint4 h = *reinterpret_cast<const uint4*>(hb + ((long)(v & 0x1ffff) << 7) + coff);
                dsumA += w;
                accA[0] = fmaf(w, __uint_as_float(h.x << 16),         accA[0]);
                accA[1] = fmaf(w, __uint_as_float(h.x & 0xffff0000u), accA[1]);
                accA[2] = fmaf(w, __uint_as_float(h.y << 16),         accA[2]);
                accA[3] = fmaf(w, __uint_as_float(h.y & 0xffff0000u), accA[3]);
                accA[4] = fmaf(w, __uint_as_float(h.z << 16),         accA[4]);
                accA[5] = fmaf(w, __uint_as_float(h.z & 0xffff0000u), accA[5]);
                accA[6] = fmaf(w, __uint_as_float(h.w << 16),         accA[6]);
                accA[7] = fmaf(w, __uint_as_float(h.w & 0xffff0000u), accA[7]);
            }
        }
        if (lenB > 0) {
            const float ad = a_d[nB];
            for (int j = sB; j < eBnd; ++j) {
                uint v = esrc[j];
                float e = a_s[v & 0x1ffff] + ad;
                e = (e >= 0.0f) ? e : 0.2f * e;
                float w = __expf(e);
                uint4 h = *reinterpret_cast<const uint4*>(hb + ((long)(v & 0x1ffff) << 7) + coff);
                dsumB += w;
                accB[0] = fmaf(w, __uint_as_float(h.x << 16),         accB[0]);
                accB[1] = fmaf(w, __uint_as_float(h.x & 0xffff0000u), accB[1]);
                accB[2] = fmaf(w, __uint_as_float(h.y << 16),         accB[2]);
                accB[3] = fmaf(w, __uint_as_float(h.y & 0xffff0000u), accB[3]);
                accB[4] = fmaf(w, __uint_as_float(h.z << 16),         accB[4]);
                accB[5] = fmaf(w, __uint_as_float(h.z & 0xffff0000u), accB[5]);
                accB[6] = fmaf(w, __uint_as_float(h.w << 16),         accB[6]);
                accB[7] = fmaf(w, __uint_as_float(h.w & 0xffff0000u), accB[7]);
            }
        }
    }

    // ---- epilogue: normalize + bias + write, per chain -------------------
    const int c0 = c16 << 3;
    const float4 b0 = *reinterpret_cast<const float4*>(bias + c0);
    const float4 b1 = *reinterpret_cast<const float4*>(bias + c0 + 4);
    #pragma unroll
    for (int ch = 0; ch < 2; ++ch) {
        const float* acc = (ch == 0) ? accA : accB;
        const float dsum = (ch == 0) ? dsumA : dsumB;
        const int node   = (ch == 0) ? nA : nB;
        const int flag   = (ch == 0) ? flagA : flagB;
        if (MODE == 1 && !flag) continue;
        const float inv = 1.0f / (dsum + 1e-16f);
        float res[8];
        res[0] = fmaf(acc[0], inv, b0.x);
        res[1] = fmaf(acc[1], inv, b0.y);
        res[2] = fmaf(acc[2], inv, b0.z);
        res[3] = fmaf(acc[3], inv, b0.w);
        res[4] = fmaf(acc[4], inv, b1.x);
        res[5] = fmaf(acc[5], inv, b1.y);
        res[6] = fmaf(acc[6], inv, b1.z);
        res[7] = fmaf(acc[7], inv, b1.w);
        if (MODE == 0) {
            uint4 pk;
            pk.x = (uint)f2bf(res[0]) | ((uint)f2bf(res[1]) << 16);
            pk.y = (uint)f2bf(res[2]) | ((uint)f2bf(res[3]) << 16);
            pk.z = (uint)f2bf(res[4]) | ((uint)f2bf(res[5]) << 16);
            pk.w = (uint)f2bf(res[6]) | ((uint)f2bf(res[7]) << 16);
            *reinterpret_cast<uint4*>((ushort*)outp + ((long)node << 7) + c0) = pk;
        } else {
            float* op = (float*)outp + ((long)node << 7) + c0;
            *reinterpret_cast<float4*>(op)     = make_float4(res[0], res[1], res[2], res[3]);
            *reinterpret_cast<float4*>(op + 4) = make_float4(res[4], res[5], res[6], res[7]);
        }
    }
}

__global__ void gather_out(const float* __restrict__ h, const int* __restrict__ idx,
                           float* __restrict__ out)
{
    int g = blockIdx.x * 256 + threadIdx.x;   // over V_OUT*32 float4s
    int v = g >> 5, c4 = (g & 31) << 2;
    long src = (long)idx[v] * C_DIM + c4;
    *reinterpret_cast<float4*>(out + ((long)v * C_DIM + c4)) =
        *reinterpret_cast<const float4*>(h + src);
}

// ---------------------------------------------------------------------------
extern "C" void kernel_launch(void* const* d_in, const int* in_sizes, int n_in,
                              void* d_out, int out_size, void* d_ws, size_t ws_size,
                              hipStream_t stream)
{
    const float* emb = (const float*)d_in[0];
    const float* W1  = (const float*)d_in[1];
    const float* as1 = (const float*)d_in[2];
    const float* ad1 = (const float*)d_in[3];
    const float* b1  = (const float*)d_in[4];
    const float* W2  = (const float*)d_in[5];
    const float* as2 = (const float*)d_in[6];
    const float* ad2 = (const float*)d_in[7];
    const float* b2  = (const float*)d_in[8];
    const int* edges1 = (const int*)d_in[9];
    const int* edges2 = (const int*)d_in[10];
    const int* idxm   = (const int*)d_in[11];
    float* out = (float*)d_out;

    char* p = (char*)d_ws;
    auto alloc = [&](size_t bytes) {
        char* r = p;
        p += (bytes + 255) & ~(size_t)255;
        return r;
    };
    float*  hB   = (float*)alloc((size_t)N_NODES * C_DIM * 4);   // 51.2 MB
    ushort* hb   = (ushort*)alloc((size_t)N_NODES * C_DIM * 2);  // 25.6 MB
    ushort* a1o  = (ushort*)alloc((size_t)N_NODES * C_DIM * 2);  // 25.6 MB
    uint*   slab = (uint*)alloc((size_t)NBUCK2 * CAP * 4);       // 12.9 MB
    uint*   esrc = (uint*)alloc((size_t)EN2 * 4);                // 7.2 MB (packed)
    int*    offs = (int*)alloc((size_t)(M2 + 1) * 4);
    ushort* W1b  = (ushort*)alloc((size_t)C_DIM * C_DIM * 2);
    ushort* W2b  = (ushort*)alloc((size_t)C_DIM * C_DIM * 2);
    float*  aS   = (float*)alloc((size_t)N_NODES * 4);
    float*  aD   = (float*)alloc((size_t)N_NODES * 4);
    int*  bbase  = (int*)alloc((size_t)NBUCK2 * 4);
    // cursor + vflag contiguous -> one memset covers both
    int*  cursor = (int*)alloc((size_t)NBUCK2 * 4);
    int*  vflag  = (int*)alloc((size_t)N_NODES * 4);

    // ---- zero cursor+vflag in one memset; fused prep (W converts + vflag)
    hipMemsetAsync(cursor, 0, (size_t)((char*)vflag - (char*)cursor) + (size_t)N_NODES * 4, stream);
    prep_kernel<<<2 * PREP_WBLK + PREP_VBLK, 256, 0, stream>>>(W1, W2, W1b, W2b, idxm, vflag);

    // ---- CSR build (both layers) -----------------------------------------
    partition_kernel<<<NCHUNK, 256, 0, stream>>>(edges1, edges2, cursor, slab);
    bucket_scan<<<1, 64, 0, stream>>>(cursor, bbase);
    local_csr<<<NBUCK2, 256, 0, stream>>>(slab, cursor, bbase, offs, esrc);

    // ---- layer 1 (fp32 emb read fused into gemm staging) -----------------
    gemm_mfma<1><<<(N_NODES + 63) / 64, 256, 0, stream>>>(emb, W1b, as1, ad1, hb, aS, aD);
    aggregate<0><<<N_NODES / 32, 256, 0, stream>>>(hb, aS, aD, b1, offs, esrc, vflag, a1o, 0);

    // ---- layer 2 ---------------------------------------------------------
    gemm_mfma<0><<<(N_NODES + 63) / 64, 256, 0, stream>>>(a1o, W2b, as2, ad2, hb, aS, aD);
    aggregate<1><<<N_NODES / 32, 256, 0, stream>>>(hb, aS, aD, b2, offs, esrc, vflag, hB, N_NODES);

    // ---- final gather ----------------------------------------------------
    gather_out<<<(V_OUT * 32) / 256, 256, 0, stream>>>(hB, idxm, out);
}